// Round 1
// baseline (1134.375 us; speedup 1.0000x reference)
//
#include <hip/hip_runtime.h>

#define NLEVELS 16
#define HSIZE (1u << 19)
#define HMASK ((1u << 19) - 1u)
#define P2 73856093u
#define P3 19349663u

// res[L] = floor(16 * (2^(1/3))^L), computed in double to match np.floor(BASE_RES * B_GROWTH**L)
__constant__ int c_res[NLEVELS] = {16, 20, 25, 32, 40, 50, 64, 80,
                                   101, 128, 161, 203, 256, 322, 406, 512};

__global__ __launch_bounds__(256) void hashgrid_kernel(
    const float* __restrict__ positions,  // [npoints, 3]
    const float* __restrict__ tables,     // [16, 2^19, 2]
    float2* __restrict__ out,             // [npoints, 16] float2
    int npoints)
{
    int t = blockIdx.x * 256 + threadIdx.x;
    int p = t >> 4;
    int L = t & 15;
    if (p >= npoints) return;

    // position -> [0,1], two rounding steps to match reference exactly
    float px = (positions[3 * p + 0] + 1.0f) * 0.5f;
    float py = (positions[3 * p + 1] + 1.0f) * 0.5f;
    float pz = (positions[3 * p + 2] + 1.0f) * 0.5f;

    float rm1 = (float)(c_res[L] - 1);
    float sx = px * rm1, sy = py * rm1, sz = pz * rm1;
    float bx = floorf(sx), by = floorf(sy), bz = floorf(sz);
    float fx = sx - bx, fy = sy - by, fz = sz - bz;

    unsigned ix = (unsigned)(int)bx;
    unsigned iy = (unsigned)(int)by;
    unsigned iz = (unsigned)(int)bz;

    // per-axis hash terms (int32 wrap == uint32 wrap; % 2^19 == & HMASK)
    unsigned hx0 = ix,       hx1 = ix + 1u;
    unsigned hy0 = iy * P2,  hy1 = hy0 + P2;
    unsigned hz0 = iz * P3,  hz1 = hz0 + P3;

    const float2* __restrict__ tab = (const float2*)tables + (size_t)L * HSIZE;

    unsigned h000 = (hx0 + hy0 + hz0) & HMASK;
    unsigned h001 = (hx0 + hy0 + hz1) & HMASK;
    unsigned h010 = (hx0 + hy1 + hz0) & HMASK;
    unsigned h011 = (hx0 + hy1 + hz1) & HMASK;
    unsigned h100 = (hx1 + hy0 + hz0) & HMASK;
    unsigned h101 = (hx1 + hy0 + hz1) & HMASK;
    unsigned h110 = (hx1 + hy1 + hz0) & HMASK;
    unsigned h111 = (hx1 + hy1 + hz1) & HMASK;

    // issue all 8 gathers up-front so the compiler can overlap them
    float2 f000 = tab[h000];
    float2 f001 = tab[h001];
    float2 f010 = tab[h010];
    float2 f011 = tab[h011];
    float2 f100 = tab[h100];
    float2 f101 = tab[h101];
    float2 f110 = tab[h110];
    float2 f111 = tab[h111];

    float wx0 = 1.0f - fx, wx1 = fx;
    float wy0 = 1.0f - fy, wy1 = fy;
    float wz0 = 1.0f - fz, wz1 = fz;

    float o0 = 0.0f, o1 = 0.0f;
    float w;
    // corner order matches reference OFFSETS: dx outer, dy, dz inner
    w = wx0 * wy0 * wz0; o0 += w * f000.x; o1 += w * f000.y;
    w = wx0 * wy0 * wz1; o0 += w * f001.x; o1 += w * f001.y;
    w = wx0 * wy1 * wz0; o0 += w * f010.x; o1 += w * f010.y;
    w = wx0 * wy1 * wz1; o0 += w * f011.x; o1 += w * f011.y;
    w = wx1 * wy0 * wz0; o0 += w * f100.x; o1 += w * f100.y;
    w = wx1 * wy0 * wz1; o0 += w * f101.x; o1 += w * f101.y;
    w = wx1 * wy1 * wz0; o0 += w * f110.x; o1 += w * f110.y;
    w = wx1 * wy1 * wz1; o0 += w * f111.x; o1 += w * f111.y;

    out[t] = make_float2(o0, o1);
}

extern "C" void kernel_launch(void* const* d_in, const int* in_sizes, int n_in,
                              void* d_out, int out_size, void* d_ws, size_t ws_size,
                              hipStream_t stream) {
    const float* positions = (const float*)d_in[0];
    const float* tables = (const float*)d_in[1];
    float2* out = (float2*)d_out;
    int npoints = in_sizes[0] / 3;          // 1,048,576
    int total = npoints * NLEVELS;          // 16,777,216 threads
    int blocks = (total + 255) / 256;       // 65,536 blocks
    hashgrid_kernel<<<blocks, 256, 0, stream>>>(positions, tables, out, npoints);
}

// Round 2
// 742.932 us; speedup vs baseline: 1.5269x; 1.5269x over previous
//
#include <hip/hip_runtime.h>

#define NLEVELS 16
#define HSIZE (1u << 19)
#define HMASK ((1u << 19) - 1u)
#define P2 73856093u
#define P3 19349663u
#define BLOCKS_PER_LEVEL 4096   // 4096 blocks * 256 threads = 1,048,576 points

// res[L] = floor(16 * (2^(1/3))^L), computed in double to match np.floor(BASE_RES * B_GROWTH**L)
__constant__ int c_res[NLEVELS] = {16, 20, 25, 32, 40, 50, 64, 80,
                                   101, 128, 161, 203, 256, 322, 406, 512};

// Level-major: block b handles level (b >> 12), point chunk (b & 4095).
// All blocks of a level dispatch consecutively -> the whole machine works on
// one table (4 MiB, fits one XCD L2; trivially fits 256 MiB L3) at a time.
__global__ __launch_bounds__(256) void hashgrid_kernel(
    const float* __restrict__ positions,  // [npoints, 3]
    const float* __restrict__ tables,     // [16, 2^19, 2]
    float2* __restrict__ out,             // [npoints, 16] float2
    int npoints)
{
    int b = blockIdx.x;
    int L = b >> 12;                 // 4096 blocks per level
    int p = (b & (BLOCKS_PER_LEVEL - 1)) * 256 + threadIdx.x;
    if (p >= npoints) return;

    // position -> [0,1], two rounding steps to match reference exactly
    float px = (positions[3 * p + 0] + 1.0f) * 0.5f;
    float py = (positions[3 * p + 1] + 1.0f) * 0.5f;
    float pz = (positions[3 * p + 2] + 1.0f) * 0.5f;

    float rm1 = (float)(c_res[L] - 1);
    float sx = px * rm1, sy = py * rm1, sz = pz * rm1;
    float bx = floorf(sx), by = floorf(sy), bz = floorf(sz);
    float fx = sx - bx, fy = sy - by, fz = sz - bz;

    unsigned ix = (unsigned)(int)bx;
    unsigned iy = (unsigned)(int)by;
    unsigned iz = (unsigned)(int)bz;

    // per-axis hash terms (int32 wrap == uint32 wrap; % 2^19 == & HMASK)
    unsigned hx0 = ix,       hx1 = ix + 1u;
    unsigned hy0 = iy * P2,  hy1 = hy0 + P2;
    unsigned hz0 = iz * P3,  hz1 = hz0 + P3;

    const float2* __restrict__ tab = (const float2*)tables + (size_t)L * HSIZE;

    unsigned h000 = (hx0 + hy0 + hz0) & HMASK;
    unsigned h001 = (hx0 + hy0 + hz1) & HMASK;
    unsigned h010 = (hx0 + hy1 + hz0) & HMASK;
    unsigned h011 = (hx0 + hy1 + hz1) & HMASK;
    unsigned h100 = (hx1 + hy0 + hz0) & HMASK;
    unsigned h101 = (hx1 + hy0 + hz1) & HMASK;
    unsigned h110 = (hx1 + hy1 + hz0) & HMASK;
    unsigned h111 = (hx1 + hy1 + hz1) & HMASK;

    // issue all 8 gathers up-front so they overlap; note h1xy = h0xy+1 (mod)
    // so pairs usually share a cache line -> L1 catches the partner.
    float2 f000 = tab[h000];
    float2 f100 = tab[h100];
    float2 f010 = tab[h010];
    float2 f110 = tab[h110];
    float2 f001 = tab[h001];
    float2 f101 = tab[h101];
    float2 f011 = tab[h011];
    float2 f111 = tab[h111];

    float wx0 = 1.0f - fx, wx1 = fx;
    float wy0 = 1.0f - fy, wy1 = fy;
    float wz0 = 1.0f - fz, wz1 = fz;

    float o0 = 0.0f, o1 = 0.0f;
    float w;
    // corner order matches reference OFFSETS: dx outer, dy, dz inner
    w = wx0 * wy0 * wz0; o0 += w * f000.x; o1 += w * f000.y;
    w = wx0 * wy0 * wz1; o0 += w * f001.x; o1 += w * f001.y;
    w = wx0 * wy1 * wz0; o0 += w * f010.x; o1 += w * f010.y;
    w = wx0 * wy1 * wz1; o0 += w * f011.x; o1 += w * f011.y;
    w = wx1 * wy0 * wz0; o0 += w * f100.x; o1 += w * f100.y;
    w = wx1 * wy0 * wz1; o0 += w * f101.x; o1 += w * f101.y;
    w = wx1 * wy1 * wz0; o0 += w * f110.x; o1 += w * f110.y;
    w = wx1 * wy1 * wz1; o0 += w * f111.x; o1 += w * f111.y;

    out[(size_t)p * NLEVELS + L] = make_float2(o0, o1);
}

extern "C" void kernel_launch(void* const* d_in, const int* in_sizes, int n_in,
                              void* d_out, int out_size, void* d_ws, size_t ws_size,
                              hipStream_t stream) {
    const float* positions = (const float*)d_in[0];
    const float* tables = (const float*)d_in[1];
    float2* out = (float2*)d_out;
    int npoints = in_sizes[0] / 3;              // 1,048,576
    int blocks = NLEVELS * BLOCKS_PER_LEVEL;    // 65,536 blocks
    hashgrid_kernel<<<blocks, 256, 0, stream>>>(positions, tables, out, npoints);
}